// Round 12
// baseline (259.877 us; speedup 1.0000x reference)
//
#include <hip/hip_runtime.h>
#include <cfloat>

#define NB    32
#define ND    256
#define NK    512
#define NCOND 16
#define NHW   4096
#define PXT   64
#define MARGIN 1.3e-4f   // validated R6-R11; 2-product fast err 2*delta ~ 8.6e-5 < MARGIN
#define QCAP  16

typedef __attribute__((ext_vector_type(8))) short bf16x8;
typedef __attribute__((ext_vector_type(4))) float f32x4;

// C declared int64 in the reference; detect storage width on device.
__device__ __forceinline__ int loadC(const int* __restrict__ C, int b) {
  int orodd = 0;
#pragma unroll
  for (int i = 1; i < 32; i += 2) orodd |= C[i];
  return (orodd == 0) ? C[2 * b] : C[b];
}

// round-to-nearest-even fp32 -> bf16 (bit trick, finite inputs)
__device__ __forceinline__ unsigned short rne_bf16(float x) {
  unsigned u = __float_as_uint(x);
  u += 0x7fffu + ((u >> 16) & 1u);
  return (unsigned short)(u >> 16);
}

// async global->LDS, 16B per lane, LDS dest = uniform base + lane*16
__device__ __forceinline__ void gl2lds16(const void* g, void* l) {
  __builtin_amdgcn_global_load_lds(
      (const __attribute__((address_space(1))) void*)g,
      (__attribute__((address_space(3))) void*)l, 16, 0, 0);
}

// Exact np-replica score, z gathered from original [b][d][n] layout.
// FP op order verbatim from the passing R5-R11 kernels.
__device__ float np_score_g(const float* __restrict__ z, size_t zoff,
                            const float* __restrict__ er, float S) {
  float P0 = 0.f, P1 = 0.f, P2 = 0.f, P3 = 0.f;
  for (int ch = 0; ch < 16; ++ch) {
    const float* eb = er + ch * 16;
    float4 e0 = *(const float4*)(eb + 0);
    float4 e1 = *(const float4*)(eb + 4);
    float4 e2 = *(const float4*)(eb + 8);
    float4 e3 = *(const float4*)(eb + 12);
    float zb[16];
#pragma unroll
    for (int q = 0; q < 16; ++q)
      zb[q] = z[zoff + (size_t)(ch * 16 + q) * NHW];
    P0 = __fadd_rn(P0, __fmul_rn(zb[12], e3.x));
    P0 = __fadd_rn(P0, __fmul_rn(zb[8],  e2.x));
    P0 = __fadd_rn(P0, __fmul_rn(zb[4],  e1.x));
    P0 = __fadd_rn(P0, __fmul_rn(zb[0],  e0.x));
    P1 = __fadd_rn(P1, __fmul_rn(zb[13], e3.y));
    P1 = __fadd_rn(P1, __fmul_rn(zb[9],  e2.y));
    P1 = __fadd_rn(P1, __fmul_rn(zb[5],  e1.y));
    P1 = __fadd_rn(P1, __fmul_rn(zb[1],  e0.y));
    P2 = __fadd_rn(P2, __fmul_rn(zb[14], e3.z));
    P2 = __fadd_rn(P2, __fmul_rn(zb[10], e2.z));
    P2 = __fadd_rn(P2, __fmul_rn(zb[6],  e1.z));
    P2 = __fadd_rn(P2, __fmul_rn(zb[2],  e0.z));
    P3 = __fadd_rn(P3, __fmul_rn(zb[15], e3.w));
    P3 = __fadd_rn(P3, __fmul_rn(zb[11], e2.w));
    P3 = __fadd_rn(P3, __fmul_rn(zb[7],  e1.w));
    P3 = __fadd_rn(P3, __fmul_rn(zb[3],  e0.w));
  }
  float G = __fadd_rn(__fadd_rn(P0, P1), __fadd_rn(P2, P3));
  return __fadd_rn(S, __fmul_rn(-2.0f, G));
}

// pre-kernel: codebook bf16-hi (RNE), k-major: whi[cond][ks=d/32][code][d%32]
__global__ __launch_bounds__(256) void k_split(
    const float* __restrict__ w, unsigned short* __restrict__ whi) {
  int i = (blockIdx.x * 256 + threadIdx.x) * 4;
  float4 v = *(const float4*)&w[i];
  int ci = i >> 17, rem = i & 131071;
  int code = rem >> 8, d = rem & 255;
  int dst = (ci << 17) + ((d >> 5) << 14) + (code << 5) + (d & 31);
  ushort4 h;
  h.x = rne_bf16(v.x); h.y = rne_bf16(v.y);
  h.z = rne_bf16(v.z); h.w = rne_bf16(v.w);
  *(ushort4*)&whi[dst] = h;
}

template <int PRE>
__global__ __launch_bounds__(512, 4) void k_vq(
    const float* __restrict__ z, const int* __restrict__ Cc,
    const float* __restrict__ w, const unsigned short* __restrict__ whi,
    float* __restrict__ out) {
  // Es chunk layout (per buf): code*32 + phys*8 ushorts,
  // phys = q_logical ^ ((code>>1)&3)  -> 2-way banks on read AND write (free)
  __shared__ __align__(16) unsigned short Es[2][NK * 32];  // 64 KB double-buffer
  __shared__ float Ssh[PXT];
  __shared__ float Wmin[8][32];
  __shared__ float Thr[PXT];
  __shared__ int   qcnt[PXT], KB[PXT];
  __shared__ int   qk[PXT][QCAP];

  // XCD-aware bijective swizzle (nwg = 2048 = 8*256)
  int orig = blockIdx.x;
  int blk  = (orig & 7) * 256 + (orig >> 3);
  int b    = blk >> 6;
  int n0   = (blk & 63) * PXT;
  int c    = loadC(Cc, b);
  int t    = threadIdx.x;
  int lane = t & 63;
  int wv   = t >> 6;            // 0..7
  int mw   = wv >> 2;           // px half (32 px)
  int nw   = wv & 3;            // code quarter (128 codes)

  if (t < PXT) qcnt[t] = 0;

  const size_t zab = (size_t)b * ND * NHW;
  const size_t cbu = (size_t)c * (NK * ND);    // whi ushort base
  const int ar_n = n0 + mw * 32 + (lane & 15); // A rows: n, n+16
  const int koff = (lane >> 4) * 8;
  const float* zA = z + zab + ar_n;

  auto stageP = [&](int buf, int ks) {
    if constexpr (PRE) {
      // linear LDS dest, inverse-swizzled global src (m173)
#pragma unroll
      for (int p = 0; p < 4; ++p) {
        int code = p * 128 + wv * 16 + (lane >> 2);
        int ql   = (lane & 3) ^ ((code >> 1) & 3);
        const unsigned short* src = whi + cbu + ks * (NK * 32) + code * 32 + ql * 8;
        gl2lds16(src, &Es[buf][p * 4096 + wv * 512]);
      }
    } else {
#pragma unroll
      for (int p = 0; p < 4; ++p) {
        int code = p * 128 + (t >> 2);
        int ql   = t & 3;
        const float* sf = w + ((size_t)c * NK + code) * ND + ks * 32 + ql * 8;
        float4 f0 = *(const float4*)sf;
        float4 f1 = *(const float4*)(sf + 4);
        float xs[8] = {f0.x, f0.y, f0.z, f0.w, f1.x, f1.y, f1.z, f1.w};
        bf16x8 h;
#pragma unroll
        for (int q = 0; q < 8; ++q) h[q] = (short)rne_bf16(xs[q]);
        int phys = ql ^ ((code >> 1) & 3);
        *(bf16x8*)&Es[buf][code * 32 + phys * 8] = h;
      }
    }
  };

  float zf0[8], zf1[8];
  auto loadz = [&](int ks) {
#pragma unroll
    for (int j = 0; j < 8; ++j) {
      size_t doff = (size_t)(ks * 32 + koff + j) * NHW;
      zf0[j] = zA[doff];
      zf1[j] = zA[doff + 16];
    }
  };

  // ---- prologue: issue first stage + first z, then hide latency under S ----
  stageP(0, 0);
  loadz(0);

  // S[px]: np pairwise replica from global z (overlaps prologue staging)
  {
    int spx = t >> 3, sj = t & 7;
    size_t sb = zab + n0 + spx;
    float r0 = 0.f, r1 = 0.f;
#pragma unroll
    for (int i = 0; i < 16; ++i) {
      float v0 = z[sb + (size_t)(8 * i + sj) * NHW];
      float v1 = z[sb + (size_t)(128 + 8 * i + sj) * NHW];
      r0 = __fadd_rn(r0, __fmul_rn(v0, v0));
      r1 = __fadd_rn(r1, __fmul_rn(v1, v1));
    }
#pragma unroll
    for (int off = 1; off < 8; off <<= 1) {
      r0 = __fadd_rn(r0, __shfl_xor(r0, off));
      r1 = __fadd_rn(r1, __shfl_xor(r1, off));
    }
    if (sj == 0) Ssh[spx] = __fadd_rn(r0, r1);
  }

  f32x4 acc0[8], acc1[8];
#pragma unroll
  for (int nt = 0; nt < 8; ++nt) {
    acc0[nt] = (f32x4){0.f, 0.f, 0.f, 0.f};
    acc1[nt] = (f32x4){0.f, 0.f, 0.f, 0.f};
  }

  // ---- pipelined K-loop: 1 barrier/ks, loads span the previous MFMA phase ----
  int cur = 0;
#pragma unroll 1
  for (int ks = 0; ks < 8; ++ks) {
    // drain loads issued one MFMA-phase ago (stage(cur) + zf(ks)); fence staging
    asm volatile("s_waitcnt vmcnt(0) lgkmcnt(0)" ::: "memory");
    __builtin_amdgcn_s_barrier();
    __builtin_amdgcn_sched_barrier(0);

    // build A hi/lo from zf (consume before reissue)
    bf16x8 ah0, al0, ah1, al1;
#pragma unroll
    for (int j = 0; j < 8; ++j) {
      unsigned u0 = __float_as_uint(zf0[j]) & 0xffff0000u;
      ah0[j] = (short)(u0 >> 16);
      al0[j] = (short)rne_bf16(zf0[j] - __uint_as_float(u0));
      unsigned u1 = __float_as_uint(zf1[j]) & 0xffff0000u;
      ah1[j] = (short)(u1 >> 16);
      al1[j] = (short)rne_bf16(zf1[j] - __uint_as_float(u1));
    }

    if (ks < 7) {              // issue next tile; latency hides under MFMA below
      stageP(cur ^ 1, ks + 1); // safe: buf^1 last read before this iter's barrier
      loadz(ks + 1);
    }

    __builtin_amdgcn_s_setprio(1);
#pragma unroll
    for (int nt = 0; nt < 8; ++nt) {
      int code = nw * 128 + nt * 16 + (lane & 15);
      int phys = (lane >> 4) ^ ((code >> 1) & 3);
      bf16x8 bh = *(const bf16x8*)&Es[cur][code * 32 + phys * 8];
      acc0[nt] = __builtin_amdgcn_mfma_f32_16x16x32_bf16(ah0, bh, acc0[nt], 0, 0, 0);
      acc0[nt] = __builtin_amdgcn_mfma_f32_16x16x32_bf16(al0, bh, acc0[nt], 0, 0, 0);
      acc1[nt] = __builtin_amdgcn_mfma_f32_16x16x32_bf16(ah1, bh, acc1[nt], 0, 0, 0);
      acc1[nt] = __builtin_amdgcn_mfma_f32_16x16x32_bf16(al1, bh, acc1[nt], 0, 0, 0);
    }
    __builtin_amdgcn_s_setprio(0);
    cur ^= 1;
  }

  // ---- X = fl(S + fl(-2G)); per-px min over this wave's 128 codes ----
  float pmin0[4], pmin1[4], S40[4], S41[4];
#pragma unroll
  for (int r = 0; r < 4; ++r) {
    int pr = mw * 32 + (lane >> 4) * 4 + r;
    S40[r] = Ssh[pr];
    S41[r] = Ssh[pr + 16];
    pmin0[r] = FLT_MAX; pmin1[r] = FLT_MAX;
  }
#pragma unroll
  for (int nt = 0; nt < 8; ++nt)
#pragma unroll
    for (int r = 0; r < 4; ++r) {
      float X0 = __fadd_rn(S40[r], __fmul_rn(-2.0f, acc0[nt][r]));
      float X1 = __fadd_rn(S41[r], __fmul_rn(-2.0f, acc1[nt][r]));
      acc0[nt][r] = X0; acc1[nt][r] = X1;
      pmin0[r] = fminf(pmin0[r], X0);
      pmin1[r] = fminf(pmin1[r], X1);
    }
#pragma unroll
  for (int r = 0; r < 4; ++r)
#pragma unroll
    for (int off = 1; off < 16; off <<= 1) {
      pmin0[r] = fminf(pmin0[r], __shfl_xor(pmin0[r], off));
      pmin1[r] = fminf(pmin1[r], __shfl_xor(pmin1[r], off));
    }
  if ((lane & 15) == 0) {
#pragma unroll
    for (int r = 0; r < 4; ++r) {
      Wmin[wv][(lane >> 4) * 4 + r]      = pmin0[r];
      Wmin[wv][16 + (lane >> 4) * 4 + r] = pmin1[r];
    }
  }
  __syncthreads();
  if (t < PXT) {
    int m2 = (t >> 5) * 4, i = t & 31;
    Thr[t] = fminf(fminf(Wmin[m2][i], Wmin[m2 + 1][i]),
                   fminf(Wmin[m2 + 2][i], Wmin[m2 + 3][i])) + MARGIN;
  }
  __syncthreads();

  // ---- enqueue candidates ----
#pragma unroll
  for (int r = 0; r < 4; ++r) {
    int px0 = mw * 32 + (lane >> 4) * 4 + r;
    float th0 = Thr[px0], th1 = Thr[px0 + 16];
#pragma unroll
    for (int nt = 0; nt < 8; ++nt) {
      int kcode = nw * 128 + nt * 16 + (lane & 15);
      if (acc0[nt][r] <= th0) {
        int slot = atomicAdd(&qcnt[px0], 1);
        if (slot < QCAP) qk[px0][slot] = kcode;
      }
      if (acc1[nt][r] <= th1) {
        int slot = atomicAdd(&qcnt[px0 + 16], 1);
        if (slot < QCAP) qk[px0 + 16][slot] = kcode;
      }
    }
  }
  __syncthreads();

  // ---- exact np re-score (wave wv: px octet, slot = lane&7) ----
  {
    int px  = wv * 8 + (lane >> 3);
    int cnt = qcnt[px]; cnt = cnt < QCAP ? cnt : QCAP;
    float S = Ssh[px];
    size_t zoff = zab + n0 + px;
    float bv = FLT_MAX; int bk = 0x7fffffff;
#pragma unroll
    for (int m = 0; m < 2; ++m) {
      int slot = (lane & 7) + 8 * m;
      if (__any(slot < cnt)) {
        if (slot < cnt) {
          int k = qk[px][slot];
          float v = np_score_g(z, zoff, w + ((size_t)c * NK + k) * ND, S);
          if (v < bv || (v == bv && k < bk)) { bv = v; bk = k; }
        }
      }
    }
#pragma unroll
    for (int off = 1; off < 8; off <<= 1) {
      float ov = __shfl_xor(bv, off);
      int   ok = __shfl_xor(bk, off);
      if (ov < bv || (ov == bv && ok < bk)) { bv = ov; bk = ok; }
    }
    if ((lane & 7) == 0) KB[px] = bk;
  }
  __syncthreads();

  // ---- gather + transpose-write both outputs (z re-read, L2-hot) ----
  {
    int px = t & 63, dg = t >> 6;
    int kidx = KB[px];
    const float* er = w + ((size_t)c * NK + kidx) * ND;
    const size_t OUT2 = (size_t)NB * ND * NHW;
    size_t base = zab + n0 + px;
#pragma unroll
    for (int j = 0; j < 32; ++j) {
      int d = dg * 32 + j;
      float q  = er[d];
      float zv = z[base + (size_t)d * NHW];
      out[base + (size_t)d * NHW]        = __fadd_rn(zv, __fsub_rn(q, zv));
      out[base + (size_t)d * NHW + OUT2] = q;
    }
  }
}

extern "C" void kernel_launch(void* const* d_in, const int* in_sizes, int n_in,
                              void* d_out, int out_size, void* d_ws, size_t ws_size,
                              hipStream_t stream) {
  const float* z = (const float*)d_in[0];
  const int*   C = (const int*)d_in[1];
  const float* w = (const float*)d_in[2];
  float* out = (float*)d_out;

  const size_t NWEL = (size_t)NCOND * NK * ND;   // 2,097,152
  unsigned short* whi = (unsigned short*)d_ws;
  bool pre = ws_size >= NWEL * sizeof(unsigned short);  // 4 MB

  if (pre) {
    k_split<<<(int)(NWEL / 1024), 256, 0, stream>>>(w, whi);
    k_vq<1><<<NB * (NHW / PXT), 512, 0, stream>>>(z, C, w, whi, out);
  } else {
    k_vq<0><<<NB * (NHW / PXT), 512, 0, stream>>>(z, C, w, whi, out);
  }
}

// Round 13
// 233.169 us; speedup vs baseline: 1.1145x; 1.1145x over previous
//
#include <hip/hip_runtime.h>
#include <cfloat>

#define NB    32
#define ND    256
#define NK    512
#define NCOND 16
#define NHW   4096
#define PXT   64
#define MARGIN 1.3e-4f   // validated R6-R12; 2-product fast err 2*delta ~ 8.6e-5 < MARGIN
#define QCAP  16

typedef __attribute__((ext_vector_type(8))) short bf16x8;
typedef __attribute__((ext_vector_type(4))) float f32x4;

// C declared int64 in the reference; detect storage width on device.
__device__ __forceinline__ int loadC(const int* __restrict__ C, int b) {
  int orodd = 0;
#pragma unroll
  for (int i = 1; i < 32; i += 2) orodd |= C[i];
  return (orodd == 0) ? C[2 * b] : C[b];
}

// round-to-nearest-even fp32 -> bf16 (bit trick, finite inputs)
__device__ __forceinline__ unsigned short rne_bf16(float x) {
  unsigned u = __float_as_uint(x);
  u += 0x7fffu + ((u >> 16) & 1u);
  return (unsigned short)(u >> 16);
}

// Exact np-replica score, z gathered from original [b][d][n] layout.
// FP op order verbatim from the passing R5-R12 kernels.
__device__ float np_score_g(const float* __restrict__ z, size_t zoff,
                            const float* __restrict__ er, float S) {
  float P0 = 0.f, P1 = 0.f, P2 = 0.f, P3 = 0.f;
  for (int ch = 0; ch < 16; ++ch) {
    const float* eb = er + ch * 16;
    float4 e0 = *(const float4*)(eb + 0);
    float4 e1 = *(const float4*)(eb + 4);
    float4 e2 = *(const float4*)(eb + 8);
    float4 e3 = *(const float4*)(eb + 12);
    float zb[16];
#pragma unroll
    for (int q = 0; q < 16; ++q)
      zb[q] = z[zoff + (size_t)(ch * 16 + q) * NHW];
    P0 = __fadd_rn(P0, __fmul_rn(zb[12], e3.x));
    P0 = __fadd_rn(P0, __fmul_rn(zb[8],  e2.x));
    P0 = __fadd_rn(P0, __fmul_rn(zb[4],  e1.x));
    P0 = __fadd_rn(P0, __fmul_rn(zb[0],  e0.x));
    P1 = __fadd_rn(P1, __fmul_rn(zb[13], e3.y));
    P1 = __fadd_rn(P1, __fmul_rn(zb[9],  e2.y));
    P1 = __fadd_rn(P1, __fmul_rn(zb[5],  e1.y));
    P1 = __fadd_rn(P1, __fmul_rn(zb[1],  e0.y));
    P2 = __fadd_rn(P2, __fmul_rn(zb[14], e3.z));
    P2 = __fadd_rn(P2, __fmul_rn(zb[10], e2.z));
    P2 = __fadd_rn(P2, __fmul_rn(zb[6],  e1.z));
    P2 = __fadd_rn(P2, __fmul_rn(zb[2],  e0.z));
    P3 = __fadd_rn(P3, __fmul_rn(zb[15], e3.w));
    P3 = __fadd_rn(P3, __fmul_rn(zb[11], e2.w));
    P3 = __fadd_rn(P3, __fmul_rn(zb[7],  e1.w));
    P3 = __fadd_rn(P3, __fmul_rn(zb[3],  e0.w));
  }
  float G = __fadd_rn(__fadd_rn(P0, P1), __fadd_rn(P2, P3));
  return __fadd_rn(S, __fmul_rn(-2.0f, G));
}

// pre-kernel: codebook bf16-hi (RNE), k-major: whi[cond][ks=d/32][code][d%32]
__global__ __launch_bounds__(256) void k_split(
    const float* __restrict__ w, unsigned short* __restrict__ whi) {
  int i = (blockIdx.x * 256 + threadIdx.x) * 4;
  float4 v = *(const float4*)&w[i];
  int ci = i >> 17, rem = i & 131071;
  int code = rem >> 8, d = rem & 255;
  int dst = (ci << 17) + ((d >> 5) << 14) + (code << 5) + (d & 31);
  ushort4 h;
  h.x = rne_bf16(v.x); h.y = rne_bf16(v.y);
  h.z = rne_bf16(v.z); h.w = rne_bf16(v.w);
  *(ushort4*)&whi[dst] = h;
}

// swizzled ushort index into Zh/Zl: row px (256 ushorts), 8-elem chunk XOR
__device__ __forceinline__ int zofs(int px, int chunk) {
  return px * 256 + ((chunk ^ (px & 7)) * 8);
}

template <int PRE>
__global__ __launch_bounds__(512, 4) void k_vq(
    const float* __restrict__ z, const int* __restrict__ Cc,
    const float* __restrict__ w, const unsigned short* __restrict__ whi,
    float* __restrict__ out) {
  __shared__ __align__(16) unsigned short Zh[PXT * ND];  // 32 KB z-hi (trunc)
  __shared__ __align__(16) unsigned short Zl[PXT * ND];  // 32 KB z-lo (rne resid)
  __shared__ float Ssh[PXT];
  __shared__ float Wmin[8][32];
  __shared__ float Thr[PXT];
  __shared__ int   qcnt[PXT], KB[PXT];
  __shared__ int   qk[PXT][QCAP];

  // XCD-aware bijective swizzle (nwg = 2048 = 8*256)
  int orig = blockIdx.x;
  int blk  = (orig & 7) * 256 + (orig >> 3);
  int b    = blk >> 6;
  int n0   = (blk & 63) * PXT;
  int c    = loadC(Cc, b);
  int t    = threadIdx.x;
  int lane = t & 63;
  int wv   = t >> 6;            // 0..7
  int mw   = wv >> 2;           // px half (32 px)
  int nw   = wv & 3;            // code quarter (128 codes)

  if (t < PXT) qcnt[t] = 0;

  const size_t zab = (size_t)b * ND * NHW;
  const size_t cbu = (size_t)c * (NK * ND);    // whi ushort base
  const int ar0  = mw * 32 + (lane & 15);      // A px rows: ar0, ar0+16
  const int koff = (lane >> 4) * 8;

  // ---- prologue A: pre-split z tile into bf16 hi/lo LDS (one-time) ----
  // thread: px = t&63 (coalesced n), wave (t>>6) owns 4 chunks = 32 d's
  {
    int px = t & 63, dg = t >> 6;
    const float* zp = z + zab + n0 + px;
#pragma unroll
    for (int cc4 = 0; cc4 < 4; ++cc4) {
      int chunk = dg * 4 + cc4;
      bf16x8 h, l;
#pragma unroll
      for (int j = 0; j < 8; ++j) {
        float v = zp[(size_t)(chunk * 8 + j) * NHW];
        unsigned u = __float_as_uint(v) & 0xffff0000u;
        h[j] = (short)(u >> 16);
        l[j] = (short)rne_bf16(v - __uint_as_float(u));
      }
      *(bf16x8*)&Zh[zofs(px, chunk)] = h;
      *(bf16x8*)&Zl[zofs(px, chunk)] = l;
    }
  }

  // ---- prologue B: S[px] np pairwise replica from global z ----
  {
    int spx = t >> 3, sj = t & 7;
    size_t sb = zab + n0 + spx;
    float r0 = 0.f, r1 = 0.f;
#pragma unroll
    for (int i = 0; i < 16; ++i) {
      float v0 = z[sb + (size_t)(8 * i + sj) * NHW];
      float v1 = z[sb + (size_t)(128 + 8 * i + sj) * NHW];
      r0 = __fadd_rn(r0, __fmul_rn(v0, v0));
      r1 = __fadd_rn(r1, __fmul_rn(v1, v1));
    }
#pragma unroll
    for (int off = 1; off < 8; off <<= 1) {
      r0 = __fadd_rn(r0, __shfl_xor(r0, off));
      r1 = __fadd_rn(r1, __shfl_xor(r1, off));
    }
    if (sj == 0) Ssh[spx] = __fadd_rn(r0, r1);
  }
  __syncthreads();   // Zh/Zl (and Ssh) ready; the ONLY barrier before epilogue

  f32x4 acc0[8], acc1[8];
#pragma unroll
  for (int nt = 0; nt < 8; ++nt) {
    acc0[nt] = (f32x4){0.f, 0.f, 0.f, 0.f};
    acc1[nt] = (f32x4){0.f, 0.f, 0.f, 0.f};
  }

  // ---- barrier-free K-loop: A from LDS, B from global (L1/L2-hot) ----
#pragma unroll 1
  for (int ks = 0; ks < 8; ++ks) {
    int chunkA = ks * 4 + (lane >> 4);
    bf16x8 ah0 = *(const bf16x8*)&Zh[zofs(ar0,      chunkA)];
    bf16x8 al0 = *(const bf16x8*)&Zl[zofs(ar0,      chunkA)];
    bf16x8 ah1 = *(const bf16x8*)&Zh[zofs(ar0 + 16, chunkA)];
    bf16x8 al1 = *(const bf16x8*)&Zl[zofs(ar0 + 16, chunkA)];
#pragma unroll
    for (int nt = 0; nt < 8; ++nt) {
      int code = nw * 128 + nt * 16 + (lane & 15);
      bf16x8 bh;
      if constexpr (PRE) {
        bh = *(const bf16x8*)(whi + cbu + ks * (NK * 32) + code * 32 + koff);
      } else {
        const float* sf = w + ((size_t)c * NK + code) * ND + ks * 32 + koff;
        float4 f0 = *(const float4*)sf;
        float4 f1 = *(const float4*)(sf + 4);
        float xs[8] = {f0.x, f0.y, f0.z, f0.w, f1.x, f1.y, f1.z, f1.w};
#pragma unroll
        for (int q = 0; q < 8; ++q) bh[q] = (short)rne_bf16(xs[q]);
      }
      acc0[nt] = __builtin_amdgcn_mfma_f32_16x16x32_bf16(ah0, bh, acc0[nt], 0, 0, 0);
      acc0[nt] = __builtin_amdgcn_mfma_f32_16x16x32_bf16(al0, bh, acc0[nt], 0, 0, 0);
      acc1[nt] = __builtin_amdgcn_mfma_f32_16x16x32_bf16(ah1, bh, acc1[nt], 0, 0, 0);
      acc1[nt] = __builtin_amdgcn_mfma_f32_16x16x32_bf16(al1, bh, acc1[nt], 0, 0, 0);
    }
  }

  // ---- X = fl(S + fl(-2G)); per-px min over this wave's 128 codes ----
  float pmin0[4], pmin1[4], S40[4], S41[4];
#pragma unroll
  for (int r = 0; r < 4; ++r) {
    int pr = mw * 32 + (lane >> 4) * 4 + r;
    S40[r] = Ssh[pr];
    S41[r] = Ssh[pr + 16];
    pmin0[r] = FLT_MAX; pmin1[r] = FLT_MAX;
  }
#pragma unroll
  for (int nt = 0; nt < 8; ++nt)
#pragma unroll
    for (int r = 0; r < 4; ++r) {
      float X0 = __fadd_rn(S40[r], __fmul_rn(-2.0f, acc0[nt][r]));
      float X1 = __fadd_rn(S41[r], __fmul_rn(-2.0f, acc1[nt][r]));
      acc0[nt][r] = X0; acc1[nt][r] = X1;
      pmin0[r] = fminf(pmin0[r], X0);
      pmin1[r] = fminf(pmin1[r], X1);
    }
#pragma unroll
  for (int r = 0; r < 4; ++r)
#pragma unroll
    for (int off = 1; off < 16; off <<= 1) {
      pmin0[r] = fminf(pmin0[r], __shfl_xor(pmin0[r], off));
      pmin1[r] = fminf(pmin1[r], __shfl_xor(pmin1[r], off));
    }
  if ((lane & 15) == 0) {
#pragma unroll
    for (int r = 0; r < 4; ++r) {
      Wmin[wv][(lane >> 4) * 4 + r]      = pmin0[r];
      Wmin[wv][16 + (lane >> 4) * 4 + r] = pmin1[r];
    }
  }
  __syncthreads();
  if (t < PXT) {
    int m2 = (t >> 5) * 4, i = t & 31;
    Thr[t] = fminf(fminf(Wmin[m2][i], Wmin[m2 + 1][i]),
                   fminf(Wmin[m2 + 2][i], Wmin[m2 + 3][i])) + MARGIN;
  }
  __syncthreads();

  // ---- enqueue candidates ----
#pragma unroll
  for (int r = 0; r < 4; ++r) {
    int px0 = mw * 32 + (lane >> 4) * 4 + r;
    float th0 = Thr[px0], th1 = Thr[px0 + 16];
#pragma unroll
    for (int nt = 0; nt < 8; ++nt) {
      int kcode = nw * 128 + nt * 16 + (lane & 15);
      if (acc0[nt][r] <= th0) {
        int slot = atomicAdd(&qcnt[px0], 1);
        if (slot < QCAP) qk[px0][slot] = kcode;
      }
      if (acc1[nt][r] <= th1) {
        int slot = atomicAdd(&qcnt[px0 + 16], 1);
        if (slot < QCAP) qk[px0 + 16][slot] = kcode;
      }
    }
  }
  __syncthreads();

  // ---- exact np re-score (wave wv: px octet, slot = lane&7) ----
  {
    int px  = wv * 8 + (lane >> 3);
    int cnt = qcnt[px]; cnt = cnt < QCAP ? cnt : QCAP;
    float S = Ssh[px];
    size_t zoff = zab + n0 + px;
    float bv = FLT_MAX; int bk = 0x7fffffff;
#pragma unroll
    for (int m = 0; m < 2; ++m) {
      int slot = (lane & 7) + 8 * m;
      if (__any(slot < cnt)) {
        if (slot < cnt) {
          int k = qk[px][slot];
          float v = np_score_g(z, zoff, w + ((size_t)c * NK + k) * ND, S);
          if (v < bv || (v == bv && k < bk)) { bv = v; bk = k; }
        }
      }
    }
#pragma unroll
    for (int off = 1; off < 8; off <<= 1) {
      float ov = __shfl_xor(bv, off);
      int   ok = __shfl_xor(bk, off);
      if (ov < bv || (ov == bv && ok < bk)) { bv = ov; bk = ok; }
    }
    if ((lane & 7) == 0) KB[px] = bk;
  }
  __syncthreads();

  // ---- gather + transpose-write both outputs (z re-read, L2-hot) ----
  {
    int px = t & 63, dg = t >> 6;
    int kidx = KB[px];
    const float* er = w + ((size_t)c * NK + kidx) * ND;
    const size_t OUT2 = (size_t)NB * ND * NHW;
    size_t base = zab + n0 + px;
#pragma unroll
    for (int j = 0; j < 32; ++j) {
      int d = dg * 32 + j;
      float q  = er[d];
      float zv = z[base + (size_t)d * NHW];
      out[base + (size_t)d * NHW]        = __fadd_rn(zv, __fsub_rn(q, zv));
      out[base + (size_t)d * NHW + OUT2] = q;
    }
  }
}

extern "C" void kernel_launch(void* const* d_in, const int* in_sizes, int n_in,
                              void* d_out, int out_size, void* d_ws, size_t ws_size,
                              hipStream_t stream) {
  const float* z = (const float*)d_in[0];
  const int*   C = (const int*)d_in[1];
  const float* w = (const float*)d_in[2];
  float* out = (float*)d_out;

  const size_t NWEL = (size_t)NCOND * NK * ND;   // 2,097,152
  unsigned short* whi = (unsigned short*)d_ws;
  bool pre = ws_size >= NWEL * sizeof(unsigned short);  // 4 MB

  if (pre) {
    k_split<<<(int)(NWEL / 1024), 256, 0, stream>>>(w, whi);
    k_vq<1><<<NB * (NHW / PXT), 512, 0, stream>>>(z, C, w, whi, out);
  } else {
    k_vq<0><<<NB * (NHW / PXT), 512, 0, stream>>>(z, C, w, whi, out);
  }
}